// Round 3
// baseline (47.369 us; speedup 1.0000x reference)
//
#include <hip/hip_runtime.h>

#define NB 2
#define NT 4
#define NN 4096
#define NBT (NB*NT)
#define TOTAL (NBT*NN)        // 32768 points per tensor
#define BIGF 1e10f
#define THRESHF 1e9f
#define NEGF (-1e10f)

// ws layout (bytes):
//   packedT : [0,              TOTAL*16)   (x,y,z, ||.||^2 + bias)
//   packedP : [TOTAL*16,       TOTAL*32)
//   minp    : [TOTAL*32,       TOTAL*36)   (uint bits of float, all >= 0)
//   mint    : [TOTAL*36,       TOTAL*40)

__global__ __launch_bounds__(256) void prep_kernel(
    const float* __restrict__ pred, const float* __restrict__ targ,
    const int* __restrict__ ic, const int* __restrict__ pad, const int* __restrict__ vis,
    float4* __restrict__ packedP, float4* __restrict__ packedT,
    unsigned* __restrict__ minp, unsigned* __restrict__ mint,
    float* __restrict__ out)
{
    int i = blockIdx.x * 256 + threadIdx.x;
    if (i == 0) out[0] = 0.0f;              // zero output each call (poison-safe)
    if (i >= TOTAL) return;
    int bt = i >> 12;                        // /NN
    int n  = i & (NN - 1);
    int b  = bt >> 2;                        // /NT
    bool m = (ic[b*NN + n] == 0) && (pad[b*NN + n] != 0) && (vis[i] != 0);
    float bias = m ? 0.0f : BIGF;
    float px = pred[3*i], py = pred[3*i+1], pz = pred[3*i+2];
    float tx = targ[3*i], ty = targ[3*i+1], tz = targ[3*i+2];
    packedP[i] = make_float4(px, py, pz, fmaf(px,px, fmaf(py,py, pz*pz)) + bias);
    packedT[i] = make_float4(tx, ty, tz, fmaf(tx,tx, fmaf(ty,ty, tz*tz)) + bias);
    minp[i] = __float_as_uint(BIGF);
    mint[i] = __float_as_uint(BIGF);
}

#define COLS 256   // columns staged per block (4 KB LDS)
#define RPT  8     // rows per thread
// grid: (colChunks=16, rowChunks=2, NBT*2=16), block=256
__global__ __launch_bounds__(256, 4) void min_kernel(
    const float4* __restrict__ packedP, const float4* __restrict__ packedT,
    unsigned* __restrict__ minp, unsigned* __restrict__ mint)
{
    __shared__ float4 cols[COLS];
    const int tid = threadIdx.x;
    const int cc  = blockIdx.x;
    const int rc  = blockIdx.y;
    const int z   = blockIdx.z;
    const int bt  = z >> 1;
    const int dir = z & 1;
    const float4* __restrict__ rowsPtr = dir ? packedT : packedP;
    const float4* __restrict__ colsPtr = dir ? packedP : packedT;
    unsigned* outp = dir ? mint : minp;
    const int base = bt * NN;

    // stage columns with -2 folded in; keep biased norm in .w
    float4 c = colsPtr[base + cc*COLS + tid];
    cols[tid] = make_float4(-2.0f*c.x, -2.0f*c.y, -2.0f*c.z, c.w);
    __syncthreads();

    const int r = base + rc*(256*RPT) + tid;
    float4 a[RPT];
    float  w[RPT];   // unbiased row norm, added after the min
    float  m[RPT];
    #pragma unroll
    for (int k = 0; k < RPT; ++k) {
        a[k] = rowsPtr[r + k*256];
        w[k] = fmaf(a[k].x,a[k].x, fmaf(a[k].y,a[k].y, a[k].z*a[k].z));
        m[k] = 3.4e38f;
    }

    #pragma unroll 4
    for (int j = 0; j < COLS; ++j) {
        float4 t = cols[j];
        #pragma unroll
        for (int k = 0; k < RPT; ++k) {
            float d = fmaf(a[k].x, t.x, fmaf(a[k].y, t.y, fmaf(a[k].z, t.z, t.w)));
            m[k] = fminf(m[k], d);
        }
    }

    // add row norm once, clamp at 0 (min/max commute), publish
    #pragma unroll
    for (int k = 0; k < RPT; ++k) {
        float v = fmaxf(m[k] + w[k], 0.0f);
        atomicMin(&outp[r + k*256], __float_as_uint(v));
    }
}

// one block per (b,t): cd + soft-hausdorff, atomicAdd contribution into out[0]
__global__ __launch_bounds__(256) void finalize_kernel(
    const unsigned* __restrict__ minp, const unsigned* __restrict__ mint,
    const int* __restrict__ ic, const int* __restrict__ pad, const int* __restrict__ vis,
    float* __restrict__ out)
{
    const int bt = blockIdx.x;
    const int b  = bt >> 2;
    const int tid = threadIdx.x;

    float hp[16], ht[16];
    float nv = 0.f, scdp = 0.f, scdt = 0.f, mhp = NEGF, mht = NEGF;
    #pragma unroll
    for (int k = 0; k < 16; ++k) {
        int n  = tid + k*256;
        int gi = bt*NN + n;
        bool m = (ic[b*NN + n] == 0) && (pad[b*NN + n] != 0) && (vis[gi] != 0);
        float mp = __uint_as_float(minp[gi]);
        float mt = __uint_as_float(mint[gi]);
        float hpv = m ? fminf(mp, THRESHF) : NEGF;
        float htv = m ? fminf(mt, THRESHF) : NEGF;
        hp[k] = hpv; ht[k] = htv;
        if (m) {
            nv += 1.f;
            scdp += (mp > THRESHF) ? 0.f : mp;
            scdt += (mt > THRESHF) ? 0.f : mt;
            mhp = fmaxf(mhp, hpv);
            mht = fmaxf(mht, htv);
        }
    }

    __shared__ float red[4][5];
    const int wid = tid >> 6;
    #pragma unroll
    for (int o = 32; o > 0; o >>= 1) {
        nv   += __shfl_xor(nv, o);
        scdp += __shfl_xor(scdp, o);
        scdt += __shfl_xor(scdt, o);
        mhp   = fmaxf(mhp, __shfl_xor(mhp, o));
        mht   = fmaxf(mht, __shfl_xor(mht, o));
    }
    if ((tid & 63) == 0) {
        red[wid][0] = nv; red[wid][1] = scdp; red[wid][2] = scdt;
        red[wid][3] = mhp; red[wid][4] = mht;
    }
    __syncthreads();
    nv   = red[0][0] + red[1][0] + red[2][0] + red[3][0];
    scdp = red[0][1] + red[1][1] + red[2][1] + red[3][1];
    scdt = red[0][2] + red[1][2] + red[2][2] + red[3][2];
    mhp  = fmaxf(fmaxf(red[0][3], red[1][3]), fmaxf(red[2][3], red[3][3]));
    mht  = fmaxf(fmaxf(red[0][4], red[1][4]), fmaxf(red[2][4], red[3][4]));
    __syncthreads();

    float Zp = 0.f, Sp = 0.f, Zt = 0.f, St = 0.f;
    #pragma unroll
    for (int k = 0; k < 16; ++k) {
        float hpv = hp[k];
        if (hpv > -THRESHF) { float e = __expf((hpv - mhp) * 10.0f); Zp += e; Sp += hpv * e; }
        float htv = ht[k];
        if (htv > -THRESHF) { float e = __expf((htv - mht) * 10.0f); Zt += e; St += htv * e; }
    }
    #pragma unroll
    for (int o = 32; o > 0; o >>= 1) {
        Zp += __shfl_xor(Zp, o);
        Sp += __shfl_xor(Sp, o);
        Zt += __shfl_xor(Zt, o);
        St += __shfl_xor(St, o);
    }
    if ((tid & 63) == 0) {
        red[wid][0] = Zp; red[wid][1] = Sp; red[wid][2] = Zt; red[wid][3] = St;
    }
    __syncthreads();
    if (tid == 0) {
        Zp = red[0][0] + red[1][0] + red[2][0] + red[3][0];
        Sp = red[0][1] + red[1][1] + red[2][1] + red[3][1];
        Zt = red[0][2] + red[1][2] + red[2][2] + red[3][2];
        St = red[0][3] + red[1][3] + red[2][3] + red[3][3];
        float nvm = fmaxf(nv, 1.f);
        float cd  = scdp / nvm + scdt / nvm;
        float sp  = (nv > 0.f) ? (Sp / Zp) : 0.f;
        float st  = (nv > 0.f) ? (St / Zt) : 0.f;
        float hd  = fmaxf(sp, st);
        atomicAdd(out, (0.5f * cd + 0.5f * hd) * 0.125f);
    }
}

extern "C" void kernel_launch(void* const* d_in, const int* in_sizes, int n_in,
                              void* d_out, int out_size, void* d_ws, size_t ws_size,
                              hipStream_t stream)
{
    const float* pred = (const float*)d_in[0];
    const float* targ = (const float*)d_in[1];
    const int*   ic   = (const int*)d_in[2];
    const int*   pad  = (const int*)d_in[3];
    const int*   vis  = (const int*)d_in[4];
    float* out = (float*)d_out;

    char* ws = (char*)d_ws;
    float4*   packedT = (float4*)(ws);
    float4*   packedP = (float4*)(ws + (size_t)TOTAL * 16);
    unsigned* minp    = (unsigned*)(ws + (size_t)TOTAL * 32);
    unsigned* mint    = (unsigned*)(ws + (size_t)TOTAL * 32 + (size_t)TOTAL * 4);

    prep_kernel<<<TOTAL/256, 256, 0, stream>>>(pred, targ, ic, pad, vis,
                                               packedP, packedT, minp, mint, out);
    dim3 grid(NN/COLS, NN/(256*RPT), NBT*2);   // (16, 2, 16)
    min_kernel<<<grid, 256, 0, stream>>>(packedP, packedT, minp, mint);
    finalize_kernel<<<NBT, 256, 0, stream>>>(minp, mint, ic, pad, vis, out);
}

// Round 5
// 40.546 us; speedup vs baseline: 1.1683x; 1.1683x over previous
//
#include <hip/hip_runtime.h>

#define NB 2
#define NT 4
#define NN 4096
#define NBT (NB*NT)
#define TOTAL (NBT*NN)        // 32768 points per tensor
#define BIGF 1e10f
#define THRESHF 1e9f
#define NEGF (-1e10f)

typedef __attribute__((ext_vector_type(8))) short s16x8;
typedef __attribute__((ext_vector_type(4))) float f32x4;

// round-to-nearest-even f32 -> bf16 (raw bits)
__device__ inline unsigned short f2bf(float f) {
    unsigned u = __float_as_uint(f);
    u += 0x7fffu + ((u >> 16) & 1u);
    return (unsigned short)(u >> 16);
}
// split x into bf16 hi + bf16 lo (lo = rn(x - hi)); pa+pb represents x to ~2^-17 rel
__device__ inline void split2(float x, unsigned short& hi, unsigned short& lo) {
    hi = f2bf(x);
    float fh = __uint_as_float(((unsigned)hi) << 16);
    lo = f2bf(x - fh);
}
__device__ inline s16x8 mk8(unsigned short a, unsigned short b, unsigned short c, unsigned short d,
                            unsigned short e, unsigned short f, unsigned short g, unsigned short h) {
    return (s16x8){(short)a,(short)b,(short)c,(short)d,(short)e,(short)f,(short)g,(short)h};
}

// Synthetic K=16 (slots 16..31 are zero), verified-layout 16x16x32 bf16 MFMA.
// Row point p (split pa+pb), col point t (u = -2t split ua+ub), wp=||p||^2, wt=||t||^2+bias:
//   row k0-7 : pax,pay,paz,pbx,pby,pbz,pax,pay    col k0-7 : uax,uay,uaz,uax,uay,uaz,ubx,uby
//   row k8-15: paz,pbx,pby,pbz,one,one,wph,wpl    col k8-15: ubz,ubx,uby,ubz,wth,wtl,one,one
// => D[r,c] = (pa+pb)·(ua+ub) + wt + wp = wp + wt - 2 p·t  (full split product, ~1e-5 abs err)
// A/B frag: lane l -> row/col = l&15, k-chunk = l>>4 (chunks 2,3 fed zeros via lanes 32-63).
// C/D frag: col = lane&15, row = 4*(lane>>4) + reg   [guide m89/m91, HW-verified]

__global__ __launch_bounds__(256) void prep_kernel(
    const float* __restrict__ pred, const float* __restrict__ targ,
    const int* __restrict__ ic, const int* __restrict__ pad, const int* __restrict__ vis,
    s16x8* __restrict__ rowP, s16x8* __restrict__ rowT,
    s16x8* __restrict__ colP, s16x8* __restrict__ colT,
    unsigned* __restrict__ minp, unsigned* __restrict__ mint,
    float* __restrict__ out)
{
    int i = blockIdx.x * 256 + threadIdx.x;
    if (i == 0) out[0] = 0.0f;              // zero output each call (poison-safe)
    if (i >= TOTAL) return;
    int bt = i >> 12;
    int n  = i & (NN - 1);
    int b  = bt >> 2;
    bool m = (ic[b*NN + n] == 0) && (pad[b*NN + n] != 0) && (vis[i] != 0);
    float bias = m ? 0.0f : BIGF;
    const unsigned short one = 0x3F80;
    int crec = bt*8192 + (n >> 4)*32 + (n & 15);   // 256 tiles/bt, 32 records/tile

    {   // pred: rows for dir=0, cols for dir=1
        float x = pred[3*i], y = pred[3*i+1], z = pred[3*i+2];
        unsigned short ax,ay,az,bx,by,bz,wh,wl, ux,uy,uz,vx,vy,vz,ch,cl;
        split2(x,ax,bx); split2(y,ay,by); split2(z,az,bz);
        float w = fmaf(x,x, fmaf(y,y, z*z));
        split2(w, wh, wl);
        split2(-2.0f*x,ux,vx); split2(-2.0f*y,uy,vy); split2(-2.0f*z,uz,vz);
        split2(w + bias, ch, cl);
        rowP[i]         = mk8(ax,ay,az,bx,by,bz,ax,ay);
        rowP[TOTAL + i] = mk8(az,bx,by,bz,one,one,wh,wl);
        colP[crec]      = mk8(ux,uy,uz,ux,uy,uz,vx,vy);
        colP[crec + 16] = mk8(vz,vx,vy,vz,ch,cl,one,one);
    }
    {   // targ
        float x = targ[3*i], y = targ[3*i+1], z = targ[3*i+2];
        unsigned short ax,ay,az,bx,by,bz,wh,wl, ux,uy,uz,vx,vy,vz,ch,cl;
        split2(x,ax,bx); split2(y,ay,by); split2(z,az,bz);
        float w = fmaf(x,x, fmaf(y,y, z*z));
        split2(w, wh, wl);
        split2(-2.0f*x,ux,vx); split2(-2.0f*y,uy,vy); split2(-2.0f*z,uz,vz);
        split2(w + bias, ch, cl);
        rowT[i]         = mk8(ax,ay,az,bx,by,bz,ax,ay);
        rowT[TOTAL + i] = mk8(az,bx,by,bz,one,one,wh,wl);
        colT[crec]      = mk8(ux,uy,uz,ux,uy,uz,vx,vy);
        colT[crec + 16] = mk8(vz,vx,vy,vz,ch,cl,one,one);
    }

    minp[i] = __float_as_uint(BIGF);
    mint[i] = __float_as_uint(BIGF);
}

// grid (8 colChunks, 16 rowChunks, 16 bt*dir), block 256 = 4 waves.
// Wave owns 64 rows (4 x 16-row tiles); block stages 512 cols = 32 col-tiles (16 KB LDS).
__global__ __launch_bounds__(256, 2) void min_kernel(
    const s16x8* __restrict__ rowP, const s16x8* __restrict__ rowT,
    const s16x8* __restrict__ colP, const s16x8* __restrict__ colT,
    unsigned* __restrict__ minp, unsigned* __restrict__ mint)
{
    __shared__ s16x8 ldsB[1024];   // 16 KB
    const int tid  = threadIdx.x;
    const int lane = tid & 63;
    const int w    = tid >> 6;
    const int cc   = blockIdx.x;
    const int rc   = blockIdx.y;
    const int z    = blockIdx.z;
    const int bt   = z >> 1;
    const int dir  = z & 1;
    const s16x8* __restrict__ rowf = dir ? rowT : rowP;
    const s16x8* __restrict__ colf = dir ? colP : colT;
    unsigned* outp = dir ? mint : minp;

    // stage 32 col-tiles (1024 records of 16B)
    const s16x8* src = colf + bt*8192 + cc*1024;
    ldsB[tid]       = src[tid];
    ldsB[tid + 256] = src[tid + 256];
    ldsB[tid + 512] = src[tid + 512];
    ldsB[tid + 768] = src[tid + 768];
    __syncthreads();

    const int g = lane >> 4;        // k-chunk 0..3
    const int j = lane & 15;        // row/col within tile
    const bool lo32 = (lane < 32);  // chunks 0,1 carry data; 2,3 are zero
    const int n0 = rc*256 + w*64;
    const s16x8 zero8 = (s16x8){0,0,0,0,0,0,0,0};
    const f32x4 zf = (f32x4){0.f,0.f,0.f,0.f};

    s16x8 a[4];
    f32x4 mm[4];
    const s16x8* rowbase = rowf + (g & 1)*TOTAL + bt*NN + n0 + j;
    #pragma unroll
    for (int rt = 0; rt < 4; ++rt) {
        a[rt] = lo32 ? rowbase[rt*16] : zero8;
        mm[rt] = (f32x4){3.4e38f, 3.4e38f, 3.4e38f, 3.4e38f};
    }

    #pragma unroll 2
    for (int ct = 0; ct < 32; ++ct) {
        s16x8 bf = lo32 ? ldsB[ct*32 + (lane & 31)] : zero8;
        #pragma unroll
        for (int rt = 0; rt < 4; ++rt) {
            f32x4 D = __builtin_amdgcn_mfma_f32_16x16x32_bf16(a[rt], bf, zf, 0, 0, 0);
            mm[rt][0] = fminf(mm[rt][0], D[0]);
            mm[rt][1] = fminf(mm[rt][1], D[1]);
            mm[rt][2] = fminf(mm[rt][2], D[2]);
            mm[rt][3] = fminf(mm[rt][3], D[3]);
        }
    }

    // min across the 16 columns: butterfly over lane bits 0-3 (stays within each 16-lane group)
    #pragma unroll
    for (int off = 1; off <= 8; off <<= 1) {
        #pragma unroll
        for (int rt = 0; rt < 4; ++rt) {
            mm[rt][0] = fminf(mm[rt][0], __shfl_xor(mm[rt][0], off));
            mm[rt][1] = fminf(mm[rt][1], __shfl_xor(mm[rt][1], off));
            mm[rt][2] = fminf(mm[rt][2], __shfl_xor(mm[rt][2], off));
            mm[rt][3] = fminf(mm[rt][3], __shfl_xor(mm[rt][3], off));
        }
    }

    // publish: thread with j<4 owns reg j; row_in_tile = 4*g + j  [verified C/D mapping]
    if (j < 4) {
        const int rb = bt*NN + n0 + 4*g + j;
        #pragma unroll
        for (int rt = 0; rt < 4; ++rt) {
            float x = (j == 0) ? mm[rt][0] : (j == 1) ? mm[rt][1] : (j == 2) ? mm[rt][2] : mm[rt][3];
            unsigned bits = __float_as_uint(fmaxf(x, 0.0f));
            if (!(x == x))               bits = __float_as_uint(BIGF);  // NaN guard
            if (bits == 0x80000000u)     bits = 0u;                     // -0 -> +0
            atomicMin(&outp[rb + rt*16], bits);
        }
    }
}

// one block per (b,t): cd + soft-hausdorff, atomicAdd contribution into out[0]
__global__ __launch_bounds__(256) void finalize_kernel(
    const unsigned* __restrict__ minp, const unsigned* __restrict__ mint,
    const int* __restrict__ ic, const int* __restrict__ pad, const int* __restrict__ vis,
    float* __restrict__ out)
{
    const int bt = blockIdx.x;
    const int b  = bt >> 2;
    const int tid = threadIdx.x;

    float hp[16], ht[16];
    float nv = 0.f, scdp = 0.f, scdt = 0.f, mhp = NEGF, mht = NEGF;
    #pragma unroll
    for (int k = 0; k < 16; ++k) {
        int n  = tid + k*256;
        int gi = bt*NN + n;
        bool m = (ic[b*NN + n] == 0) && (pad[b*NN + n] != 0) && (vis[gi] != 0);
        float mp = __uint_as_float(minp[gi]);
        float mt = __uint_as_float(mint[gi]);
        if (!(mp <= 2e10f)) mp = BIGF;   // NaN/garbage guard (legit values <= ~1.1e10)
        if (!(mt <= 2e10f)) mt = BIGF;
        float hpv = m ? fminf(mp, THRESHF) : NEGF;
        float htv = m ? fminf(mt, THRESHF) : NEGF;
        hp[k] = hpv; ht[k] = htv;
        if (m) {
            nv += 1.f;
            scdp += (mp > THRESHF) ? 0.f : mp;
            scdt += (mt > THRESHF) ? 0.f : mt;
            mhp = fmaxf(mhp, hpv);
            mht = fmaxf(mht, htv);
        }
    }

    __shared__ float red[4][5];
    const int wid = tid >> 6;
    #pragma unroll
    for (int o = 32; o > 0; o >>= 1) {
        nv   += __shfl_xor(nv, o);
        scdp += __shfl_xor(scdp, o);
        scdt += __shfl_xor(scdt, o);
        mhp   = fmaxf(mhp, __shfl_xor(mhp, o));
        mht   = fmaxf(mht, __shfl_xor(mht, o));
    }
    if ((tid & 63) == 0) {
        red[wid][0] = nv; red[wid][1] = scdp; red[wid][2] = scdt;
        red[wid][3] = mhp; red[wid][4] = mht;
    }
    __syncthreads();
    nv   = red[0][0] + red[1][0] + red[2][0] + red[3][0];
    scdp = red[0][1] + red[1][1] + red[2][1] + red[3][1];
    scdt = red[0][2] + red[1][2] + red[2][2] + red[3][2];
    mhp  = fmaxf(fmaxf(red[0][3], red[1][3]), fmaxf(red[2][3], red[3][3]));
    mht  = fmaxf(fmaxf(red[0][4], red[1][4]), fmaxf(red[2][4], red[3][4]));
    __syncthreads();

    float Zp = 0.f, Sp = 0.f, Zt = 0.f, St = 0.f;
    #pragma unroll
    for (int k = 0; k < 16; ++k) {
        float hpv = hp[k];
        if (hpv > -THRESHF) { float e = __expf((hpv - mhp) * 10.0f); Zp += e; Sp += hpv * e; }
        float htv = ht[k];
        if (htv > -THRESHF) { float e = __expf((htv - mht) * 10.0f); Zt += e; St += htv * e; }
    }
    #pragma unroll
    for (int o = 32; o > 0; o >>= 1) {
        Zp += __shfl_xor(Zp, o);
        Sp += __shfl_xor(Sp, o);
        Zt += __shfl_xor(Zt, o);
        St += __shfl_xor(St, o);
    }
    if ((tid & 63) == 0) {
        red[wid][0] = Zp; red[wid][1] = Sp; red[wid][2] = Zt; red[wid][3] = St;
    }
    __syncthreads();
    if (tid == 0) {
        Zp = red[0][0] + red[1][0] + red[2][0] + red[3][0];
        Sp = red[0][1] + red[1][1] + red[2][1] + red[3][1];
        Zt = red[0][2] + red[1][2] + red[2][2] + red[3][2];
        St = red[0][3] + red[1][3] + red[2][3] + red[3][3];
        float nvm = fmaxf(nv, 1.f);
        float cd  = scdp / nvm + scdt / nvm;
        float sp  = (nv > 0.f) ? (Sp / Zp) : 0.f;
        float st  = (nv > 0.f) ? (St / Zt) : 0.f;
        float hd  = fmaxf(sp, st);
        atomicAdd(out, (0.5f * cd + 0.5f * hd) * 0.125f);
    }
}

extern "C" void kernel_launch(void* const* d_in, const int* in_sizes, int n_in,
                              void* d_out, int out_size, void* d_ws, size_t ws_size,
                              hipStream_t stream)
{
    const float* pred = (const float*)d_in[0];
    const float* targ = (const float*)d_in[1];
    const int*   ic   = (const int*)d_in[2];
    const int*   pad  = (const int*)d_in[3];
    const int*   vis  = (const int*)d_in[4];
    float* out = (float*)d_out;

    char* ws = (char*)d_ws;
    s16x8* rowP = (s16x8*)ws;
    s16x8* rowT = rowP + 2*TOTAL;
    s16x8* colP = rowT + 2*TOTAL;
    s16x8* colT = colP + 2*TOTAL;
    unsigned* minp = (unsigned*)(colT + 2*TOTAL);
    unsigned* mint = minp + TOTAL;

    prep_kernel<<<TOTAL/256, 256, 0, stream>>>(pred, targ, ic, pad, vis,
                                               rowP, rowT, colP, colT, minp, mint, out);
    dim3 grid(8, 16, 16);
    min_kernel<<<grid, 256, 0, stream>>>(rowP, rowT, colP, colT, minp, mint);
    finalize_kernel<<<NBT, 256, 0, stream>>>(minp, mint, ic, pad, vis, out);
}